// Round 6
// baseline (120.494 us; speedup 1.0000x reference)
//
#include <hip/hip_runtime.h>

#define DEV __device__ __forceinline__

typedef _Float16 half8 __attribute__((ext_vector_type(8)));
typedef _Float16 half2v __attribute__((ext_vector_type(2)));
typedef float f32x16 __attribute__((ext_vector_type(16)));
typedef int int4v __attribute__((ext_vector_type(4)));

DEV f32x16 mfma16(half8 a, half8 b, f32x16 c) {
    return __builtin_amdgcn_mfma_f32_32x32x16_f16(a, b, c, 0, 0, 0);
}
DEV half8 h8(int4v v) { return __builtin_bit_cast(half8, v); }
DEV half8 ldh8(const _Float16* p) { return *(const half8*)p; }
DEV int pkrtz(float a, float b) {
    auto t = __builtin_amdgcn_cvt_pkrtz(a, b);
    return __builtin_bit_cast(int, t);
}
// pack two f32 -> f16x2 (RTZ), then packed relu
DEV int relupk(float a, float b) {
    int p = pkrtz(a, b);
    half2v h = __builtin_bit_cast(half2v, p);
    half2v z = {(_Float16)0.f, (_Float16)0.f};
    h = __builtin_elementwise_max(h, z);   // v_pk_max_f16
    return __builtin_bit_cast(int, h);
}
// v_permlane32_swap_b32: a[32..63] <-> b[0..31]
DEV void plswap(int& a, int& b) {
    asm("v_permlane32_swap_b32 %0, %1" : "+v"(a), "+v"(b));
}

DEV f32x16 zero16() {
    f32x16 z = {0.f,0.f,0.f,0.f,0.f,0.f,0.f,0.f,0.f,0.f,0.f,0.f,0.f,0.f,0.f,0.f};
    return z;
}

struct Frags { int4v c[4]; };  // activation B-fragments, K=64 (4 chunks of 16)

// relu + pack + cross-half swap: D-layout -> next layer's B-frag layout (verified R0)
DEV void repack(const f32x16& C0, const f32x16& C1, Frags& B) {
    int P0[8], P1[8];
#pragma unroll
    for (int q = 0; q < 8; ++q) {
        P0[q] = relupk(C0[2*q], C0[2*q+1]);
        P1[q] = relupk(C1[2*q], C1[2*q+1]);
    }
#pragma unroll
    for (int kk = 0; kk < 4; ++kk) {
        const int* Pm = (kk < 2) ? P0 : P1;
        int idx = 4 * (kk & 1);
        int a0 = Pm[idx + 0], b0 = Pm[idx + 2];
        int a1 = Pm[idx + 1], b1 = Pm[idx + 3];
        plswap(a0, b0);
        plswap(a1, b1);
        int4v nb; nb[0] = a0; nb[1] = a1; nb[2] = b0; nb[3] = b1;
        B.c[kk] = nb;
    }
}

// hidden layer, kk-major: 4 accumulators in flight, A-chunks streamed (2 live at a time)
DEV void hid_step(const _Float16* wb, int lam, int4v ones, Frags& B0, Frags& B1) {
    const _Float16* p0 = wb + lam * 8;
    const _Float16* p1 = wb + 2560 + lam * 8;
    half8 a40 = ldh8(p0 + 2048);   // bias chunk kk=4
    half8 a41 = ldh8(p1 + 2048);
    f32x16 C00 = mfma16(a40, h8(ones), zero16());
    f32x16 C01 = mfma16(a41, h8(ones), zero16());
    f32x16 C10 = mfma16(a40, h8(ones), zero16());
    f32x16 C11 = mfma16(a41, h8(ones), zero16());
#pragma unroll
    for (int kk = 0; kk < 4; ++kk) {
        half8 a0 = ldh8(p0 + kk * 512);
        half8 a1 = ldh8(p1 + kk * 512);
        half8 b0 = h8(B0.c[kk]);
        half8 b1 = h8(B1.c[kk]);
        C00 = mfma16(a0, b0, C00);
        C01 = mfma16(a1, b0, C01);
        C10 = mfma16(a0, b1, C10);
        C11 = mfma16(a1, b1, C11);
    }
    repack(C00, C01, B0);
    repack(C10, C11, B1);
}

// input layer, kk-major: K=32 (bias rides in k=28 slot of x), no bias MFMA
DEV void in_step(const _Float16* wb, int lam, Frags& B0, Frags& B1) {
    const _Float16* p0 = wb + lam * 8;
    const _Float16* p1 = wb + 1024 + lam * 8;
    f32x16 C00, C01, C10, C11;
    {
        half8 a0 = ldh8(p0);
        half8 a1 = ldh8(p1);
        half8 b0 = h8(B0.c[0]);
        half8 b1 = h8(B1.c[0]);
        C00 = mfma16(a0, b0, zero16());
        C01 = mfma16(a1, b0, zero16());
        C10 = mfma16(a0, b1, zero16());
        C11 = mfma16(a1, b1, zero16());
    }
    {
        half8 a0 = ldh8(p0 + 512);
        half8 a1 = ldh8(p1 + 512);
        half8 b0 = h8(B0.c[1]);
        half8 b1 = h8(B1.c[1]);
        C00 = mfma16(a0, b0, C00);
        C01 = mfma16(a1, b0, C01);
        C10 = mfma16(a0, b1, C10);
        C11 = mfma16(a1, b1, C11);
    }
    repack(C00, C01, B0);
    repack(C10, C11, B1);
}

// out layer, kk-major: A shared across the pair, streamed
DEV void out_step2(const _Float16* wb, int lam, int4v ones,
                   const Frags& B0, const Frags& B1, float* __restrict__ out, int row0, int row1) {
    const int h = lam >> 5;
    const _Float16* p = wb + lam * 8;
    half8 a4 = ldh8(p + 2048);
    f32x16 Ca = mfma16(a4, h8(ones), zero16());
    f32x16 Cb = mfma16(a4, h8(ones), zero16());
#pragma unroll
    for (int kk = 0; kk < 4; ++kk) {
        half8 a = ldh8(p + kk * 512);
        Ca = mfma16(a, h8(B0.c[kk]), Ca);
        Cb = mfma16(a, h8(B1.c[kk]), Cb);
    }
    float* oa = out + row0 * 21;
    float* ob = out + row1 * 21;
#pragma unroll
    for (int r = 0; r < 16; ++r) {
        int f = (r & 3) + 8 * (r >> 2) + 4 * h;
        if (f < 21) {
            oa[f] = __builtin_amdgcn_rcpf(1.f + __expf(-Ca[r]));
            ob[f] = __builtin_amdgcn_rcpf(1.f + __expf(-Cb[r]));
        }
    }
}

DEV void load_x(const float* __restrict__ x, int row, int h, Frags& B) {
    // k = 16*kk + 8*h + e; x row stride 28 f32; k=28 slot carries 1.0 (bias rides in wI row 28)
    const float* xr = x + row * 28;
    float4 fa = *(const float4*)(xr + 8 * h);
    float4 fb = *(const float4*)(xr + 8 * h + 4);
    float4 fc = *(const float4*)(xr + 16 + 8 * h);
    float4 fd = (h == 0) ? *(const float4*)(xr + 20) : make_float4(1.f, 0.f, 0.f, 0.f);
    int4v c0, c1;
    c0[0] = pkrtz(fa.x, fa.y); c0[1] = pkrtz(fa.z, fa.w);
    c0[2] = pkrtz(fb.x, fb.y); c0[3] = pkrtz(fb.z, fb.w);
    c1[0] = pkrtz(fc.x, fc.y); c1[1] = pkrtz(fc.z, fc.w);
    c1[2] = pkrtz(fd.x, fd.y); c1[3] = pkrtz(fd.z, fd.w);
    B.c[0] = c0; B.c[1] = c1;
}

#define NT 1024

__global__ __attribute__((amdgpu_flat_work_group_size(NT, NT), amdgpu_waves_per_eu(4, 4)))
void mlp_fused(
    const float* __restrict__ x, const float* __restrict__ W_in, const float* __restrict__ b_in,
    const float* __restrict__ W_hid, const float* __restrict__ b_hid,
    const float* __restrict__ W_out, const float* __restrict__ b_out,
    float* __restrict__ out) {
    // LDS weights in f16, A-fragment order: wH [l][m][kk 0..4][lam][e]; chunk kk=4 = bias column
    __shared__ __align__(16) _Float16 wH[51200];  // 10 x 2 x 5 x 64 x 8
    __shared__ __align__(16) _Float16 wI[2048];   // 2 x 2 x 64 x 8  (K=32, bias in k=28)
    __shared__ __align__(16) _Float16 wO[2560];   // 5 x 64 x 8      (features 0..20)

    const int tid = threadIdx.x;

    // zero phase: chunk-4 regions of wH, all of wI and wO
    for (int i = tid; i < 10240; i += NT) {   // wH bias chunks: [l][m][512]
        int l = i >> 10, rem = i & 1023, m = rem >> 9, off = rem & 511;
        wH[l * 5120 + m * 2560 + 2048 + off] = (_Float16)0.f;
    }
    for (int i = tid; i < 2048; i += NT) wI[i] = (_Float16)0.f;
    for (int i = tid; i < 2560; i += NT) wO[i] = (_Float16)0.f;
    __syncthreads();

    // fill phase (coalesced global reads, scattered LDS writes)
    for (int i = tid; i < 40960; i += NT) {   // W_hid [l][kin][o]
        int o = i & 63, kin = (i >> 6) & 63, l = i >> 12;
        int m = o >> 5, kk = kin >> 4, hh = (kin >> 3) & 1, e = kin & 7;
        int lam = hh * 32 + (o & 31);
        wH[l * 5120 + m * 2560 + kk * 512 + lam * 8 + e] = (_Float16)W_hid[i];
    }
    for (int i = tid; i < 640; i += NT) {     // b_hid -> wH chunk4, e=0, lam<32
        int l = i >> 6, f = i & 63, m = f >> 5, r = f & 31;
        wH[l * 5120 + m * 2560 + 2048 + r * 8] = (_Float16)b_hid[i];
    }
    for (int i = tid; i < 1792; i += NT) {    // W_in [28][64]
        int o = i & 63, kin = i >> 6;
        int m = o >> 5, kk = kin >> 4, hh = (kin >> 3) & 1, e = kin & 7;
        int lam = hh * 32 + (o & 31);
        wI[m * 1024 + kk * 512 + lam * 8 + e] = (_Float16)W_in[i];
    }
    for (int i = tid; i < 64; i += NT) {      // b_in -> wI k=28 slot: kk=1, hh=1, e=4
        int m = i >> 5;
        wI[m * 1024 + 512 + (32 + (i & 31)) * 8 + 4] = (_Float16)b_in[i];
    }
    for (int i = tid; i < 1344; i += NT) {    // W_out [64][21]
        int o = i % 21, kin = i / 21;
        int kk = kin >> 4, hh = (kin >> 3) & 1, e = kin & 7;
        int lam = hh * 32 + o;
        wO[kk * 512 + lam * 8 + e] = (_Float16)W_out[i];
    }
    for (int i = tid; i < 21; i += NT)        // b_out -> wO chunk4, e=0
        wO[4 * 512 + i * 8] = (_Float16)b_out[i];
    __syncthreads();

    const int w = tid >> 6, lam = tid & 63;
    const int col = lam & 31, h = lam >> 5;
    int4v ones; ones[0] = (h == 0) ? 0x3C00 : 0; ones[1] = 0; ones[2] = 0; ones[3] = 0;

    // persistent: 256 blocks x 128 tiles; wave w takes pairs pb = w*2 + 32k -> exactly 4 each
    const int tbase = blockIdx.x * 128;
#pragma unroll 1
    for (int pb = w * 2; pb < 128; pb += 32) {
        int t0 = tbase + pb;
        int row0 = t0 * 32 + col, row1 = row0 + 32;
        Frags B0, B1;
        load_x(x, row0, h, B0);
        load_x(x, row1, h, B1);
        in_step(wI, lam, B0, B1);
        const _Float16* wp = wH;
#pragma unroll 1
        for (int l = 0; l < 10; ++l) {
            hid_step(wp, lam, ones, B0, B1);
            wp += 5120;
        }
        out_step2(wO, lam, ones, B0, B1, out, row0, row1);
    }
}

extern "C" void kernel_launch(void* const* d_in, const int* in_sizes, int n_in,
                              void* d_out, int out_size, void* d_ws, size_t ws_size,
                              hipStream_t stream) {
    const float* x     = (const float*)d_in[0];
    const float* W_in  = (const float*)d_in[1];
    const float* b_in  = (const float*)d_in[2];
    const float* W_hid = (const float*)d_in[3];
    const float* b_hid = (const float*)d_in[4];
    const float* W_out = (const float*)d_in[5];
    const float* b_out = (const float*)d_in[6];
    float* out = (float*)d_out;
    mlp_fused<<<dim3(256), dim3(NT), 0, stream>>>(x, W_in, b_in, W_hid, b_hid, W_out, b_out, out);
}

// Round 7
// 116.828 us; speedup vs baseline: 1.0314x; 1.0314x over previous
//
#include <hip/hip_runtime.h>

#define DEV __device__ __forceinline__

typedef _Float16 half8 __attribute__((ext_vector_type(8)));
typedef _Float16 half2v __attribute__((ext_vector_type(2)));
typedef float f32x16 __attribute__((ext_vector_type(16)));
typedef int int4v __attribute__((ext_vector_type(4)));

DEV f32x16 mfma16(half8 a, half8 b, f32x16 c) {
    return __builtin_amdgcn_mfma_f32_32x32x16_f16(a, b, c, 0, 0, 0);
}
DEV half8 h8(int4v v) { return __builtin_bit_cast(half8, v); }
DEV half8 ldh8(const _Float16* p) { return *(const half8*)p; }
DEV int pkrtz(float a, float b) {
    auto t = __builtin_amdgcn_cvt_pkrtz(a, b);
    return __builtin_bit_cast(int, t);
}
// pack two f32 -> f16x2 (RTZ), then packed relu
DEV int relupk(float a, float b) {
    int p = pkrtz(a, b);
    half2v h = __builtin_bit_cast(half2v, p);
    half2v z = {(_Float16)0.f, (_Float16)0.f};
    h = __builtin_elementwise_max(h, z);   // v_pk_max_f16
    return __builtin_bit_cast(int, h);
}
// v_permlane32_swap_b32: a[32..63] <-> b[0..31]
DEV void plswap(int& a, int& b) {
    asm("v_permlane32_swap_b32 %0, %1" : "+v"(a), "+v"(b));
}

DEV f32x16 zero16() {
    f32x16 z = {0.f,0.f,0.f,0.f,0.f,0.f,0.f,0.f,0.f,0.f,0.f,0.f,0.f,0.f,0.f,0.f};
    return z;
}

struct Frags { int4v c[4]; };  // activation B-fragments, K=64 (4 chunks of 16)

// relu + pack + cross-half swap: D-layout -> next layer's B-frag layout (verified R0)
DEV void repack(const f32x16& C0, const f32x16& C1, Frags& B) {
    int P0[8], P1[8];
#pragma unroll
    for (int q = 0; q < 8; ++q) {
        P0[q] = relupk(C0[2*q], C0[2*q+1]);
        P1[q] = relupk(C1[2*q], C1[2*q+1]);
    }
#pragma unroll
    for (int kk = 0; kk < 4; ++kk) {
        const int* Pm = (kk < 2) ? P0 : P1;
        int idx = 4 * (kk & 1);
        int a0 = Pm[idx + 0], b0 = Pm[idx + 2];
        int a1 = Pm[idx + 1], b1 = Pm[idx + 3];
        plswap(a0, b0);
        plswap(a1, b1);
        int4v nb; nb[0] = a0; nb[1] = a1; nb[2] = b0; nb[3] = b1;
        B.c[kk] = nb;
    }
}

// hidden layer, kk-major: 4 accumulators in flight, A-chunks streamed (2 live at a time)
DEV void hid_step(const _Float16* wb, int lam, int4v ones, Frags& B0, Frags& B1) {
    const _Float16* p0 = wb + lam * 8;
    const _Float16* p1 = wb + 2560 + lam * 8;
    half8 a40 = ldh8(p0 + 2048);   // bias chunk kk=4
    half8 a41 = ldh8(p1 + 2048);
    __builtin_amdgcn_s_setprio(1);
    f32x16 C00 = mfma16(a40, h8(ones), zero16());
    f32x16 C01 = mfma16(a41, h8(ones), zero16());
    f32x16 C10 = mfma16(a40, h8(ones), zero16());
    f32x16 C11 = mfma16(a41, h8(ones), zero16());
#pragma unroll
    for (int kk = 0; kk < 4; ++kk) {
        half8 a0 = ldh8(p0 + kk * 512);
        half8 a1 = ldh8(p1 + kk * 512);
        half8 b0 = h8(B0.c[kk]);
        half8 b1 = h8(B1.c[kk]);
        C00 = mfma16(a0, b0, C00);
        C01 = mfma16(a1, b0, C01);
        C10 = mfma16(a0, b1, C10);
        C11 = mfma16(a1, b1, C11);
    }
    __builtin_amdgcn_s_setprio(0);
    repack(C00, C01, B0);
    repack(C10, C11, B1);
}

// input layer, kk-major: K=32 (bias rides in k=28 slot of x), no bias MFMA
DEV void in_step(const _Float16* wb, int lam, Frags& B0, Frags& B1) {
    const _Float16* p0 = wb + lam * 8;
    const _Float16* p1 = wb + 1024 + lam * 8;
    f32x16 C00, C01, C10, C11;
    __builtin_amdgcn_s_setprio(1);
    {
        half8 a0 = ldh8(p0);
        half8 a1 = ldh8(p1);
        half8 b0 = h8(B0.c[0]);
        half8 b1 = h8(B1.c[0]);
        C00 = mfma16(a0, b0, zero16());
        C01 = mfma16(a1, b0, zero16());
        C10 = mfma16(a0, b1, zero16());
        C11 = mfma16(a1, b1, zero16());
    }
    {
        half8 a0 = ldh8(p0 + 512);
        half8 a1 = ldh8(p1 + 512);
        half8 b0 = h8(B0.c[1]);
        half8 b1 = h8(B1.c[1]);
        C00 = mfma16(a0, b0, C00);
        C01 = mfma16(a1, b0, C01);
        C10 = mfma16(a0, b1, C10);
        C11 = mfma16(a1, b1, C11);
    }
    __builtin_amdgcn_s_setprio(0);
    repack(C00, C01, B0);
    repack(C10, C11, B1);
}

// out layer, kk-major: A shared across the pair, streamed
DEV void out_step2(const _Float16* wb, int lam, int4v ones,
                   const Frags& B0, const Frags& B1, float* __restrict__ out, int row0, int row1) {
    const int h = lam >> 5;
    const _Float16* p = wb + lam * 8;
    half8 a4 = ldh8(p + 2048);
    __builtin_amdgcn_s_setprio(1);
    f32x16 Ca = mfma16(a4, h8(ones), zero16());
    f32x16 Cb = mfma16(a4, h8(ones), zero16());
#pragma unroll
    for (int kk = 0; kk < 4; ++kk) {
        half8 a = ldh8(p + kk * 512);
        Ca = mfma16(a, h8(B0.c[kk]), Ca);
        Cb = mfma16(a, h8(B1.c[kk]), Cb);
    }
    __builtin_amdgcn_s_setprio(0);
    float* oa = out + row0 * 21;
    float* ob = out + row1 * 21;
#pragma unroll
    for (int r = 0; r < 16; ++r) {
        int f = (r & 3) + 8 * (r >> 2) + 4 * h;
        if (f < 21) {
            oa[f] = __builtin_amdgcn_rcpf(1.f + __expf(-Ca[r]));
            ob[f] = __builtin_amdgcn_rcpf(1.f + __expf(-Cb[r]));
        }
    }
}

DEV void load_x(const float* __restrict__ x, int row, int h, Frags& B) {
    // k = 16*kk + 8*h + e; x row stride 28 f32; k=28 slot carries 1.0 (bias rides in wI row 28)
    const float* xr = x + row * 28;
    float4 fa = *(const float4*)(xr + 8 * h);
    float4 fb = *(const float4*)(xr + 8 * h + 4);
    float4 fc = *(const float4*)(xr + 16 + 8 * h);
    float4 fd = (h == 0) ? *(const float4*)(xr + 20) : make_float4(1.f, 0.f, 0.f, 0.f);
    int4v c0, c1;
    c0[0] = pkrtz(fa.x, fa.y); c0[1] = pkrtz(fa.z, fa.w);
    c0[2] = pkrtz(fb.x, fb.y); c0[3] = pkrtz(fb.z, fb.w);
    c1[0] = pkrtz(fc.x, fc.y); c1[1] = pkrtz(fc.z, fc.w);
    c1[2] = pkrtz(fd.x, fd.y); c1[3] = pkrtz(fd.z, fd.w);
    B.c[0] = c0; B.c[1] = c1;
}

#define NT 1024

__global__ __attribute__((amdgpu_flat_work_group_size(NT, NT), amdgpu_waves_per_eu(4, 4)))
void mlp_fused(
    const float* __restrict__ x, const float* __restrict__ W_in, const float* __restrict__ b_in,
    const float* __restrict__ W_hid, const float* __restrict__ b_hid,
    const float* __restrict__ W_out, const float* __restrict__ b_out,
    float* __restrict__ out) {
    // LDS weights in f16, A-fragment order: wH [l][m][kk 0..4][lam][e]; chunk kk=4 = bias column
    __shared__ __align__(16) _Float16 wH[51200];  // 10 x 2 x 5 x 64 x 8
    __shared__ __align__(16) _Float16 wI[2048];   // 2 x 2 x 64 x 8  (K=32, bias in k=28)
    __shared__ __align__(16) _Float16 wO[2560];   // 5 x 64 x 8      (features 0..20)

    const int tid = threadIdx.x;

    // zero phase: chunk-4 regions of wH, all of wI and wO
    for (int i = tid; i < 10240; i += NT) {   // wH bias chunks: [l][m][512]
        int l = i >> 10, rem = i & 1023, m = rem >> 9, off = rem & 511;
        wH[l * 5120 + m * 2560 + 2048 + off] = (_Float16)0.f;
    }
    for (int i = tid; i < 2048; i += NT) wI[i] = (_Float16)0.f;
    for (int i = tid; i < 2560; i += NT) wO[i] = (_Float16)0.f;
    __syncthreads();

    // fill phase (coalesced global reads, scattered LDS writes)
    for (int i = tid; i < 40960; i += NT) {   // W_hid [l][kin][o]
        int o = i & 63, kin = (i >> 6) & 63, l = i >> 12;
        int m = o >> 5, kk = kin >> 4, hh = (kin >> 3) & 1, e = kin & 7;
        int lam = hh * 32 + (o & 31);
        wH[l * 5120 + m * 2560 + kk * 512 + lam * 8 + e] = (_Float16)W_hid[i];
    }
    for (int i = tid; i < 640; i += NT) {     // b_hid -> wH chunk4, e=0, lam<32
        int l = i >> 6, f = i & 63, m = f >> 5, r = f & 31;
        wH[l * 5120 + m * 2560 + 2048 + r * 8] = (_Float16)b_hid[i];
    }
    for (int i = tid; i < 1792; i += NT) {    // W_in [28][64]
        int o = i & 63, kin = i >> 6;
        int m = o >> 5, kk = kin >> 4, hh = (kin >> 3) & 1, e = kin & 7;
        int lam = hh * 32 + (o & 31);
        wI[m * 1024 + kk * 512 + lam * 8 + e] = (_Float16)W_in[i];
    }
    for (int i = tid; i < 64; i += NT) {      // b_in -> wI k=28 slot: kk=1, hh=1, e=4
        int m = i >> 5;
        wI[m * 1024 + 512 + (32 + (i & 31)) * 8 + 4] = (_Float16)b_in[i];
    }
    for (int i = tid; i < 1344; i += NT) {    // W_out [64][21]
        int o = i % 21, kin = i / 21;
        int kk = kin >> 4, hh = (kin >> 3) & 1, e = kin & 7;
        int lam = hh * 32 + o;
        wO[kk * 512 + lam * 8 + e] = (_Float16)W_out[i];
    }
    for (int i = tid; i < 21; i += NT)        // b_out -> wO chunk4, e=0
        wO[4 * 512 + i * 8] = (_Float16)b_out[i];
    __syncthreads();

    const int w = tid >> 6, lam = tid & 63;
    const int col = lam & 31, h = lam >> 5;
    int4v ones; ones[0] = (h == 0) ? 0x3C00 : 0; ones[1] = 0; ones[2] = 0; ones[3] = 0;

    // anti-convoy stagger: wave w starts ~w*256 cycles late (one-time, <=1.6us)
    for (int i = 0; i < w; ++i) __builtin_amdgcn_s_sleep(4);

    // persistent: 256 blocks x 128 tiles; wave w takes pairs pb = w*2 + 32k -> exactly 4 each
    const int tbase = blockIdx.x * 128;
#pragma unroll 1
    for (int pb = w * 2; pb < 128; pb += 32) {
        int t0 = tbase + pb;
        int row0 = t0 * 32 + col, row1 = row0 + 32;
        Frags B0, B1;
        load_x(x, row0, h, B0);
        load_x(x, row1, h, B1);
        in_step(wI, lam, B0, B1);
        const _Float16* wp = wH;
#pragma unroll 1
        for (int l = 0; l < 10; ++l) {
            hid_step(wp, lam, ones, B0, B1);
            wp += 5120;
        }
        out_step2(wO, lam, ones, B0, B1, out, row0, row1);
    }
}

extern "C" void kernel_launch(void* const* d_in, const int* in_sizes, int n_in,
                              void* d_out, int out_size, void* d_ws, size_t ws_size,
                              hipStream_t stream) {
    const float* x     = (const float*)d_in[0];
    const float* W_in  = (const float*)d_in[1];
    const float* b_in  = (const float*)d_in[2];
    const float* W_hid = (const float*)d_in[3];
    const float* b_hid = (const float*)d_in[4];
    const float* W_out = (const float*)d_in[5];
    const float* b_out = (const float*)d_in[6];
    float* out = (float*)d_out;
    mlp_fused<<<dim3(256), dim3(NT), 0, stream>>>(x, W_in, b_in, W_hid, b_hid, W_out, b_out, out);
}

// Round 8
// 109.460 us; speedup vs baseline: 1.1008x; 1.0673x over previous
//
#include <hip/hip_runtime.h>

#define DEV __device__ __forceinline__

typedef _Float16 half8 __attribute__((ext_vector_type(8)));
typedef _Float16 half2v __attribute__((ext_vector_type(2)));
typedef float f32x16 __attribute__((ext_vector_type(16)));
typedef int int4v __attribute__((ext_vector_type(4)));

DEV f32x16 mfma16(half8 a, half8 b, f32x16 c) {
    return __builtin_amdgcn_mfma_f32_32x32x16_f16(a, b, c, 0, 0, 0);
}
DEV half8 h8(int4v v) { return __builtin_bit_cast(half8, v); }
DEV half8 ldh8(const _Float16* p) { return *(const half8*)p; }
DEV int pkrtz(float a, float b) {
    auto t = __builtin_amdgcn_cvt_pkrtz(a, b);
    return __builtin_bit_cast(int, t);
}
// pack two f32 -> f16x2 (RTZ), then packed relu
DEV int relupk(float a, float b) {
    int p = pkrtz(a, b);
    half2v h = __builtin_bit_cast(half2v, p);
    half2v z = {(_Float16)0.f, (_Float16)0.f};
    h = __builtin_elementwise_max(h, z);   // v_pk_max_f16
    return __builtin_bit_cast(int, h);
}
// v_permlane32_swap_b32: a[32..63] <-> b[0..31]
DEV void plswap(int& a, int& b) {
    asm("v_permlane32_swap_b32 %0, %1" : "+v"(a), "+v"(b));
}

DEV f32x16 zero16() {
    f32x16 z = {0.f,0.f,0.f,0.f,0.f,0.f,0.f,0.f,0.f,0.f,0.f,0.f,0.f,0.f,0.f,0.f};
    return z;
}

struct Frags { int4v c[4]; };  // activation B-fragments, K=64 (4 chunks of 16)

// relu + pack + cross-half swap: D-layout -> next layer's B-frag layout (verified R0)
DEV void repack(const f32x16& C0, const f32x16& C1, Frags& B) {
    int P0[8], P1[8];
#pragma unroll
    for (int q = 0; q < 8; ++q) {
        P0[q] = relupk(C0[2*q], C0[2*q+1]);
        P1[q] = relupk(C1[2*q], C1[2*q+1]);
    }
#pragma unroll
    for (int kk = 0; kk < 4; ++kk) {
        const int* Pm = (kk < 2) ? P0 : P1;
        int idx = 4 * (kk & 1);
        int a0 = Pm[idx + 0], b0 = Pm[idx + 2];
        int a1 = Pm[idx + 1], b1 = Pm[idx + 3];
        plswap(a0, b0);
        plswap(a1, b1);
        int4v nb; nb[0] = a0; nb[1] = a1; nb[2] = b0; nb[3] = b1;
        B.c[kk] = nb;
    }
}

// hidden layer, quad (T=4): 8 accumulators, A-chunks shared by all 4 tiles
DEV void hid_step4(const _Float16* wb, int lam, int4v ones, const f32x16& Z, Frags* B) {
    const _Float16* p0 = wb + lam * 8;
    const _Float16* p1 = wb + 2560 + lam * 8;
    half8 a40 = ldh8(p0 + 2048);   // bias chunk kk=4
    half8 a41 = ldh8(p1 + 2048);
    f32x16 CA[4], CB[4];
    __builtin_amdgcn_s_setprio(1);
#pragma unroll
    for (int t = 0; t < 4; ++t) {
        CA[t] = mfma16(a40, h8(ones), Z);
        CB[t] = mfma16(a41, h8(ones), Z);
    }
#pragma unroll
    for (int kk = 0; kk < 4; ++kk) {
        half8 a0 = ldh8(p0 + kk * 512);
        half8 a1 = ldh8(p1 + kk * 512);
#pragma unroll
        for (int t = 0; t < 4; ++t) {
            half8 bt = h8(B[t].c[kk]);
            CA[t] = mfma16(a0, bt, CA[t]);
            CB[t] = mfma16(a1, bt, CB[t]);
        }
    }
    __builtin_amdgcn_s_setprio(0);
#pragma unroll
    for (int t = 0; t < 4; ++t) repack(CA[t], CB[t], B[t]);
}

// input layer, quad: K=32 (bias rides in k=28 slot of x), no bias MFMA
DEV void in_step4(const _Float16* wb, int lam, const f32x16& Z, Frags* B) {
    const _Float16* p0 = wb + lam * 8;
    const _Float16* p1 = wb + 1024 + lam * 8;
    f32x16 CA[4], CB[4];
    __builtin_amdgcn_s_setprio(1);
    {
        half8 a0 = ldh8(p0);
        half8 a1 = ldh8(p1);
#pragma unroll
        for (int t = 0; t < 4; ++t) {
            half8 bt = h8(B[t].c[0]);
            CA[t] = mfma16(a0, bt, Z);
            CB[t] = mfma16(a1, bt, Z);
        }
    }
    {
        half8 a0 = ldh8(p0 + 512);
        half8 a1 = ldh8(p1 + 512);
#pragma unroll
        for (int t = 0; t < 4; ++t) {
            half8 bt = h8(B[t].c[1]);
            CA[t] = mfma16(a0, bt, CA[t]);
            CB[t] = mfma16(a1, bt, CB[t]);
        }
    }
    __builtin_amdgcn_s_setprio(0);
#pragma unroll
    for (int t = 0; t < 4; ++t) repack(CA[t], CB[t], B[t]);
}

// out layer, quad: A shared across all 4 tiles; features 0..20 (m=0 half only)
DEV void out_step4(const _Float16* wb, int lam, int4v ones, const f32x16& Z,
                   const Frags* B, float* __restrict__ out, const int* rows) {
    const int h = lam >> 5;
    const _Float16* p = wb + lam * 8;
    half8 a4 = ldh8(p + 2048);
    f32x16 C[4];
    __builtin_amdgcn_s_setprio(1);
#pragma unroll
    for (int t = 0; t < 4; ++t) C[t] = mfma16(a4, h8(ones), Z);
#pragma unroll
    for (int kk = 0; kk < 4; ++kk) {
        half8 a = ldh8(p + kk * 512);
#pragma unroll
        for (int t = 0; t < 4; ++t) C[t] = mfma16(a, h8(B[t].c[kk]), C[t]);
    }
    __builtin_amdgcn_s_setprio(0);
#pragma unroll
    for (int t = 0; t < 4; ++t) {
        float* o = out + rows[t] * 21;
#pragma unroll
        for (int r = 0; r < 16; ++r) {
            int f = (r & 3) + 8 * (r >> 2) + 4 * h;
            if (f < 21) o[f] = __builtin_amdgcn_rcpf(1.f + __expf(-C[t][r]));
        }
    }
}

DEV void load_x(const float* __restrict__ x, int row, int h, Frags& B) {
    // k = 16*kk + 8*h + e; x row stride 28 f32; k=28 slot carries 1.0 (bias rides in wI row 28)
    const float* xr = x + row * 28;
    float4 fa = *(const float4*)(xr + 8 * h);
    float4 fb = *(const float4*)(xr + 8 * h + 4);
    float4 fc = *(const float4*)(xr + 16 + 8 * h);
    float4 fd = (h == 0) ? *(const float4*)(xr + 20) : make_float4(1.f, 0.f, 0.f, 0.f);
    int4v c0, c1;
    c0[0] = pkrtz(fa.x, fa.y); c0[1] = pkrtz(fa.z, fa.w);
    c0[2] = pkrtz(fb.x, fb.y); c0[3] = pkrtz(fb.z, fb.w);
    c1[0] = pkrtz(fc.x, fc.y); c1[1] = pkrtz(fc.z, fc.w);
    c1[2] = pkrtz(fd.x, fd.y); c1[3] = pkrtz(fd.z, fd.w);
    B.c[0] = c0; B.c[1] = c1;
}

#define NT 512

__global__ __attribute__((amdgpu_flat_work_group_size(NT, NT), amdgpu_waves_per_eu(2, 2)))
void mlp_fused(
    const float* __restrict__ x, const float* __restrict__ W_in, const float* __restrict__ b_in,
    const float* __restrict__ W_hid, const float* __restrict__ b_hid,
    const float* __restrict__ W_out, const float* __restrict__ b_out,
    float* __restrict__ out) {
    // LDS weights in f16, A-fragment order: wH [l][m][kk 0..4][lam][e]; chunk kk=4 = bias column
    __shared__ __align__(16) _Float16 wH[51200];  // 10 x 2 x 5 x 64 x 8
    __shared__ __align__(16) _Float16 wI[2048];   // 2 x 2 x 64 x 8  (K=32, bias in k=28)
    __shared__ __align__(16) _Float16 wO[2560];   // 5 x 64 x 8      (features 0..20)

    const int tid = threadIdx.x;

    // zero phase: chunk-4 regions of wH, all of wI and wO
    for (int i = tid; i < 10240; i += NT) {   // wH bias chunks: [l][m][512]
        int l = i >> 10, rem = i & 1023, m = rem >> 9, off = rem & 511;
        wH[l * 5120 + m * 2560 + 2048 + off] = (_Float16)0.f;
    }
    for (int i = tid; i < 2048; i += NT) wI[i] = (_Float16)0.f;
    for (int i = tid; i < 2560; i += NT) wO[i] = (_Float16)0.f;
    __syncthreads();

    // fill phase (coalesced global reads, scattered LDS writes)
    for (int i = tid; i < 40960; i += NT) {   // W_hid [l][kin][o]
        int o = i & 63, kin = (i >> 6) & 63, l = i >> 12;
        int m = o >> 5, kk = kin >> 4, hh = (kin >> 3) & 1, e = kin & 7;
        int lam = hh * 32 + (o & 31);
        wH[l * 5120 + m * 2560 + kk * 512 + lam * 8 + e] = (_Float16)W_hid[i];
    }
    for (int i = tid; i < 640; i += NT) {     // b_hid -> wH chunk4, e=0, lam<32
        int l = i >> 6, f = i & 63, m = f >> 5, r = f & 31;
        wH[l * 5120 + m * 2560 + 2048 + r * 8] = (_Float16)b_hid[i];
    }
    for (int i = tid; i < 1792; i += NT) {    // W_in [28][64]
        int o = i & 63, kin = i >> 6;
        int m = o >> 5, kk = kin >> 4, hh = (kin >> 3) & 1, e = kin & 7;
        int lam = hh * 32 + (o & 31);
        wI[m * 1024 + kk * 512 + lam * 8 + e] = (_Float16)W_in[i];
    }
    for (int i = tid; i < 64; i += NT) {      // b_in -> wI k=28 slot: kk=1, hh=1, e=4
        int m = i >> 5;
        wI[m * 1024 + 512 + (32 + (i & 31)) * 8 + 4] = (_Float16)b_in[i];
    }
    for (int i = tid; i < 1344; i += NT) {    // W_out [64][21]
        int o = i % 21, kin = i / 21;
        int kk = kin >> 4, hh = (kin >> 3) & 1, e = kin & 7;
        int lam = hh * 32 + o;
        wO[kk * 512 + lam * 8 + e] = (_Float16)W_out[i];
    }
    for (int i = tid; i < 21; i += NT)        // b_out -> wO chunk4, e=0
        wO[4 * 512 + i * 8] = (_Float16)b_out[i];
    __syncthreads();

    const int w = tid >> 6, lam = tid & 63;
    const int col = lam & 31, h = lam >> 5;
    int4v ones; ones[0] = (h == 0) ? 0x3C00 : 0; ones[1] = 0; ones[2] = 0; ones[3] = 0;
    const f32x16 Z = zero16();

    // anti-convoy: odd waves start ~832 cycles late (half a quad-layer period)
    if (w & 1) __builtin_amdgcn_s_sleep(13);

    // persistent: 256 blocks x 32 quads (quad = 4 tiles of 32 rows); wave w -> quads w+8j, exactly 4
    const int tbase = blockIdx.x * 128;
#pragma unroll 1
    for (int j = 0; j < 4; ++j) {
        int q = w + 8 * j;
        int t0 = tbase + q * 4;
        Frags B[4];
        int rows[4];
#pragma unroll
        for (int t = 0; t < 4; ++t) {
            rows[t] = (t0 + t) * 32 + col;
            load_x(x, rows[t], h, B[t]);
        }
        in_step4(wI, lam, Z, B);
        const _Float16* wp = wH;
#pragma unroll 1
        for (int l = 0; l < 10; ++l) {
            hid_step4(wp, lam, ones, Z, B);
            wp += 5120;
        }
        out_step4(wO, lam, ones, Z, B, out, rows);
    }
}

extern "C" void kernel_launch(void* const* d_in, const int* in_sizes, int n_in,
                              void* d_out, int out_size, void* d_ws, size_t ws_size,
                              hipStream_t stream) {
    const float* x     = (const float*)d_in[0];
    const float* W_in  = (const float*)d_in[1];
    const float* b_in  = (const float*)d_in[2];
    const float* W_hid = (const float*)d_in[3];
    const float* b_hid = (const float*)d_in[4];
    const float* W_out = (const float*)d_in[5];
    const float* b_out = (const float*)d_in[6];
    float* out = (float*)d_out;
    mlp_fused<<<dim3(256), dim3(NT), 0, stream>>>(x, W_in, b_in, W_hid, b_hid, W_out, b_out, out);
}